// Round 11
// baseline (62.467 us; speedup 1.0000x reference)
//
#include <hip/hip_runtime.h>

#define BB 8
#define NN 256
#define DD 128
#define SW 257  // W_msg row stride (2D+1)
#define SU 256  // W_upd row stride (2D)
#define EPSV 1e-5f

__device__ __forceinline__ float wave_reduce_add(float v) {
#pragma unroll
  for (int off = 32; off > 0; off >>= 1) v += __shfl_xor(v, off, 64);
  return v;
}

// ---------------- K1: centered u,s + per-row LN scalars + wtilde + WuT -----
// (unchanged from R10 measured-best)
__global__ __launch_bounds__(256) void k_proj(
    const float* __restrict__ h, const float* __restrict__ Wm,
    const float* __restrict__ bmsg, const float* __restrict__ Wu,
    float* __restrict__ u, float* __restrict__ s,
    float* __restrict__ rowA, float* __restrict__ rowB,
    float* __restrict__ rowD2, float* __restrict__ rowE2,
    float* __restrict__ wtilv, float* __restrict__ wut) {
  const int blk = blockIdx.x;            // 512: 64 per batch, 4 rows each
  const int b = blk >> 6;
  const int r0 = (blk & 63) * 4;
  const int tid = threadIdx.x;
  const int half = tid >> 7, e = tid & 127;
  const int wv = tid >> 6, lane = tid & 63;

  __shared__ float hs[4][DD];
  __shared__ float pS[4][4], pw[2], pQ[4][4], pD[4][4];

  const float* hb = h + (size_t)(b * NN + r0) * DD;
  if (tid < DD) {
#pragma unroll
    for (int r = 0; r < 4; ++r) hs[r][e] = hb[r * DD + e];
  }
  if (tid >= DD && tid < DD + 64) {
    const int i = blk * 64 + (tid - DD);
    const int d = i >> 7, e2 = i & 127;
    wut[i] = Wu[(size_t)e2 * SU + d];
  }
  __syncthreads();

  float acc[4];
  const float bm = (half == 0) ? bmsg[e] : 0.f;   // fold b_msg into u
#pragma unroll
  for (int r = 0; r < 4; ++r) acc[r] = bm;

  const float* wr = Wm + (size_t)e * SW + half * DD;
#pragma unroll 8
  for (int k = 0; k < DD; k += 4) {
    const float4 w4 = *(const float4*)(wr + k);
#pragma unroll
    for (int r = 0; r < 4; ++r) {
      const float4 hv = *(const float4*)(&hs[r][k]);
      acc[r] = fmaf(hv.x, w4.x, acc[r]);
      acc[r] = fmaf(hv.y, w4.y, acc[r]);
      acc[r] = fmaf(hv.z, w4.z, acc[r]);
      acc[r] = fmaf(hv.w, w4.w, acc[r]);
    }
  }

  const float we = Wm[(size_t)e * SW + 2 * DD];   // wJ[e]
#pragma unroll
  for (int r = 0; r < 4; ++r) {
    const float sm = wave_reduce_add(acc[r]);
    if (lane == 0) pS[wv][r] = sm;
  }
  {
    const float sw = wave_reduce_add(we);
    if (lane == 0 && wv < 2) pw[wv] = sw;
  }
  __syncthreads();

  const int b2 = half * 2;
  const float muw = (pw[0] + pw[1]) * (1.f / DD);
  const float wtil = we - muw;
  float c[4];
#pragma unroll
  for (int r = 0; r < 4; ++r)
    c[r] = acc[r] - (pS[b2][r] + pS[b2 + 1][r]) * (1.f / DD);

  float* outp = (half == 0 ? u : s) + (size_t)(b * NN + r0) * DD;
#pragma unroll
  for (int r = 0; r < 4; ++r) outp[r * DD + e] = c[r];
  if (blk == 0 && half == 0) wtilv[e] = wtil;

#pragma unroll
  for (int r = 0; r < 4; ++r) {
    const float q = wave_reduce_add(c[r] * c[r]);
    const float dd = wave_reduce_add(c[r] * wtil);
    if (lane == 0) { pQ[wv][r] = q; pD[wv][r] = dd; }
  }
  __syncthreads();
  if (tid < 4) {
    const int row = b * NN + r0 + tid;
    rowA[row]  = pQ[0][tid] + pQ[1][tid];
    rowD2[row] = 2.f * (pD[0][tid] + pD[1][tid]);
    rowB[row]  = pQ[2][tid] + pQ[3][tid];
    rowE2[row] = 2.f * (pD[2][tid] + pD[3][tid]);
  }
}

// ---------------- K2: fused dots + msg LN/SiLU/aggregate + upd -------------
// ONE i-row per block; 2048 blocks x 256 thr = 32 waves/CU (max occupancy).
// LDS ~18.2 KB -> 8 blocks/CU.
__global__ __launch_bounds__(256) void k_msgf1(
    const float* __restrict__ h, const float* __restrict__ u,
    const float* __restrict__ s, const float* __restrict__ adj,
    const float* __restrict__ rowA, const float* __restrict__ rowB,
    const float* __restrict__ rowD2, const float* __restrict__ rowE2,
    const float* __restrict__ wtilv, const float* __restrict__ g,
    const float* __restrict__ be, const float* __restrict__ wut,
    const float* __restrict__ bu, const float* __restrict__ gu,
    const float* __restrict__ beu, float* __restrict__ out) {
  const int blk = blockIdx.x;            // 2048 = b*256 + i
  const int b = blk >> 8, i = blk & 255;
  const int tid = threadIdx.x, lane = tid & 63, wv = tid >> 6;
  const int bNN = b * NN;

  __shared__ __align__(16) float st_[32 * 132];   // s-tile; later sacc/agg
  __shared__ __align__(16) float urow_[DD];       // u~ row; later comb
  __shared__ __align__(16) float hrow_[DD];
  __shared__ float2 pak[32];                      // {aJ, rs}
  __shared__ float pm[2], pq[2];

  // prologue
  if (tid < DD)       urow_[tid] = u[(size_t)blk * DD + tid];
  else                hrow_[tid - DD] = h[(size_t)blk * DD + (tid - DD)];
  const float2 wt2 = *(const float2*)(wtilv + 2 * lane);
  const float2 g2  = *(const float2*)(g + 2 * lane);
  const float2 be2 = *(const float2*)(be + 2 * lane);
  const float C = wave_reduce_add(fmaf(wt2.x, wt2.x, wt2.y * wt2.y));
  const float Ai = rowA[blk];
  const float D2i = rowD2[blk];
  __syncthreads();
  const float2 uu = *(const float2*)(&urow_[2 * lane]);

  float acc0 = 0.f, acc1 = 0.f;
  const float* sb = s + (size_t)bNN * DD;
  const float* adjrow = adj + (size_t)blk * NN;

  for (int tile = 0; tile < 8; ++tile) {
    const int t0 = tile * 32;
    __syncthreads();                     // st_/pak safe to overwrite
    // stage s-tile: 32 rows x 128 floats, coalesced
    {
      const int r = tid >> 5, c4 = (tid & 31) * 4;
#pragma unroll
      for (int p = 0; p < 4; ++p) {
        const int row = p * 8 + r;
        *(float4*)(&st_[row * 132 + c4]) =
            *(const float4*)(sb + (size_t)(t0 + row) * DD + c4);
      }
    }
    __syncthreads();
    // dots + rs precompute (8 lanes per j)
    {
      const int j = tid >> 3, seg = tid & 7, k0 = seg * 16;
      float d0 = 0.f;
#pragma unroll
      for (int k = 0; k < 16; k += 4) {
        const float4 sv = *(const float4*)(&st_[j * 132 + k0 + k]);
        const float4 uv = *(const float4*)(&urow_[k0 + k]);
        d0 = fmaf(sv.x, uv.x, d0); d0 = fmaf(sv.y, uv.y, d0);
        d0 = fmaf(sv.z, uv.z, d0); d0 = fmaf(sv.w, uv.w, d0);
      }
#pragma unroll
      for (int m = 1; m < 8; m <<= 1) d0 += __shfl_xor(d0, m, 64);
      if (seg == 0) {
        const int jg = t0 + j;
        const float Bj = rowB[bNN + jg], E2j = rowE2[bNN + jg];
        const float a0 = adjrow[jg];
        const float q0 = fmaf(a0, fmaf(a0, C, D2i + E2j), Ai + Bj + 2.f * d0);
        pak[j] = make_float2(a0, __builtin_amdgcn_rsqf(fmaf(q0, 1.f / DD, EPSV)));
      }
    }
    __syncthreads();
    // j-loop: all from LDS, rs precomputed, no cross-lane ops
    for (int jj = wv; jj < 32; jj += 4) {
      const int jg = t0 + jj;
      if (jg == i) continue;             // wave-uniform
      const float2 ss = *(const float2*)(&st_[jj * 132 + 2 * lane]);
      const float2 p = pak[jj];
      const float x0 = fmaf(p.x, wt2.x, uu.x + ss.x);
      const float x1 = fmaf(p.x, wt2.y, uu.y + ss.y);
      const float y0 = fmaf(x0 * p.y, g2.x, be2.x);
      const float y1 = fmaf(x1 * p.y, g2.y, be2.y);
      acc0 = fmaf(y0, __builtin_amdgcn_rcpf(1.f + __expf(-y0)), acc0);
      acc1 = fmaf(y1, __builtin_amdgcn_rcpf(1.f + __expf(-y1)), acc1);
    }
  }

  // reduce 4 waves -> agg row (overlay in st_)
  __syncthreads();
  *(float2*)(&st_[wv * DD + 2 * lane]) = make_float2(acc0, acc1);
  __syncthreads();
  if (tid < DD) {
    st_[4 * DD + tid] = st_[0 * DD + tid] + st_[1 * DD + tid] +
                        st_[2 * DD + tid] + st_[3 * DD + tid];
  }
  __syncthreads();

  // upd tail: v[e] = bu[e] + h.Wu1 + agg.Wu2 (split halves)
  const int half = tid >> 7, e = tid & 127;
  float v = (half == 0) ? bu[e] : 0.f;
  {
    const float* xin = (half == 0) ? hrow_ : &st_[4 * DD];
    const float* wcol = wut + (size_t)half * DD * DD + e;
#pragma unroll 8
    for (int k = 0; k < DD; ++k) v = fmaf(xin[k], wcol[(size_t)k * DD], v);
  }
  if (half == 1) urow_[e] = v;           // comb (urow_ dead after dots)
  __syncthreads();
  if (half == 0) {
    v += urow_[e];
    const float sm = wave_reduce_add(v), sq = wave_reduce_add(v * v);
    if (lane == 0) { pm[wv] = sm; pq[wv] = sq; }
  }
  __syncthreads();
  if (half == 0) {
    const float mean = (pm[0] + pm[1]) * (1.f / DD);
    const float var = (pq[0] + pq[1]) * (1.f / DD) - mean * mean;
    const float rs = __builtin_amdgcn_rsqf(var + EPSV);
    const float y = fmaf((v - mean) * rs, gu[e], beu[e]);
    const float sg = __builtin_amdgcn_rcpf(1.f + __expf(-y));
    out[(size_t)blk * DD + e] = hrow_[e] + y * sg;
  }
}

extern "C" void kernel_launch(void* const* d_in, const int* in_sizes, int n_in,
                              void* d_out, int out_size, void* d_ws, size_t ws_size,
                              hipStream_t stream) {
  const float* h    = (const float*)d_in[0];
  const float* adj  = (const float*)d_in[1];
  const float* Wm   = (const float*)d_in[2];
  const float* bmsg = (const float*)d_in[3];
  const float* gmsg = (const float*)d_in[4];
  const float* bemsg= (const float*)d_in[5];
  const float* Wu   = (const float*)d_in[6];
  const float* bupd = (const float*)d_in[7];
  const float* gupd = (const float*)d_in[8];
  const float* beupd= (const float*)d_in[9];
  float* out = (float*)d_out;

  float* ws    = (float*)d_ws;
  float* u     = ws;                        // 262144
  float* s     = u + BB * NN * DD;          // 262144
  float* rowA  = s + BB * NN * DD;          // 2048
  float* rowB  = rowA + BB * NN;            // 2048
  float* rowD2 = rowB + BB * NN;            // 2048
  float* rowE2 = rowD2 + BB * NN;           // 2048
  float* wtilv = rowE2 + BB * NN;           // 128
  float* wut   = wtilv + DD;                // 32768

  k_proj<<<512, 256, 0, stream>>>(h, Wm, bmsg, Wu, u, s, rowA, rowB, rowD2,
                                  rowE2, wtilv, wut);
  k_msgf1<<<2048, 256, 0, stream>>>(h, u, s, adj, rowA, rowB, rowD2, rowE2,
                                    wtilv, gmsg, bemsg, wut, bupd, gupd,
                                    beupd, out);
}

// Round 12
// 56.484 us; speedup vs baseline: 1.1059x; 1.1059x over previous
//
#include <hip/hip_runtime.h>

#define BB 8
#define NN 256
#define DD 128
#define SW 257  // W_msg row stride (2D+1)
#define SU 256  // W_upd row stride (2D)
#define EPSV 1e-5f

__device__ __forceinline__ float wave_reduce_add(float v) {
#pragma unroll
  for (int off = 32; off > 0; off >>= 1) v += __shfl_xor(v, off, 64);
  return v;
}

// ---------------- K1: centered u,s + per-row LN scalars + wtilde + WuT -----
// (unchanged, measured-best)
__global__ __launch_bounds__(256) void k_proj(
    const float* __restrict__ h, const float* __restrict__ Wm,
    const float* __restrict__ bmsg, const float* __restrict__ Wu,
    float* __restrict__ u, float* __restrict__ s,
    float* __restrict__ rowA, float* __restrict__ rowB,
    float* __restrict__ rowD2, float* __restrict__ rowE2,
    float* __restrict__ wtilv, float* __restrict__ wut) {
  const int blk = blockIdx.x;            // 512: 64 per batch, 4 rows each
  const int b = blk >> 6;
  const int r0 = (blk & 63) * 4;
  const int tid = threadIdx.x;
  const int half = tid >> 7, e = tid & 127;
  const int wv = tid >> 6, lane = tid & 63;

  __shared__ float hs[4][DD];
  __shared__ float pS[4][4], pw[2], pQ[4][4], pD[4][4];

  const float* hb = h + (size_t)(b * NN + r0) * DD;
  if (tid < DD) {
#pragma unroll
    for (int r = 0; r < 4; ++r) hs[r][e] = hb[r * DD + e];
  }
  if (tid >= DD && tid < DD + 64) {
    const int i = blk * 64 + (tid - DD);
    const int d = i >> 7, e2 = i & 127;
    wut[i] = Wu[(size_t)e2 * SU + d];
  }
  __syncthreads();

  float acc[4];
  const float bm = (half == 0) ? bmsg[e] : 0.f;   // fold b_msg into u
#pragma unroll
  for (int r = 0; r < 4; ++r) acc[r] = bm;

  const float* wr = Wm + (size_t)e * SW + half * DD;
#pragma unroll 8
  for (int k = 0; k < DD; k += 4) {
    const float4 w4 = *(const float4*)(wr + k);
#pragma unroll
    for (int r = 0; r < 4; ++r) {
      const float4 hv = *(const float4*)(&hs[r][k]);
      acc[r] = fmaf(hv.x, w4.x, acc[r]);
      acc[r] = fmaf(hv.y, w4.y, acc[r]);
      acc[r] = fmaf(hv.z, w4.z, acc[r]);
      acc[r] = fmaf(hv.w, w4.w, acc[r]);
    }
  }

  const float we = Wm[(size_t)e * SW + 2 * DD];   // wJ[e]
#pragma unroll
  for (int r = 0; r < 4; ++r) {
    const float sm = wave_reduce_add(acc[r]);
    if (lane == 0) pS[wv][r] = sm;
  }
  {
    const float sw = wave_reduce_add(we);
    if (lane == 0 && wv < 2) pw[wv] = sw;
  }
  __syncthreads();

  const int b2 = half * 2;
  const float muw = (pw[0] + pw[1]) * (1.f / DD);
  const float wtil = we - muw;
  float c[4];
#pragma unroll
  for (int r = 0; r < 4; ++r)
    c[r] = acc[r] - (pS[b2][r] + pS[b2 + 1][r]) * (1.f / DD);

  float* outp = (half == 0 ? u : s) + (size_t)(b * NN + r0) * DD;
#pragma unroll
  for (int r = 0; r < 4; ++r) outp[r * DD + e] = c[r];
  if (blk == 0 && half == 0) wtilv[e] = wtil;

#pragma unroll
  for (int r = 0; r < 4; ++r) {
    const float q = wave_reduce_add(c[r] * c[r]);
    const float dd = wave_reduce_add(c[r] * wtil);
    if (lane == 0) { pQ[wv][r] = q; pD[wv][r] = dd; }
  }
  __syncthreads();
  if (tid < 4) {
    const int row = b * NN + r0 + tid;
    rowA[row]  = pQ[0][tid] + pQ[1][tid];
    rowD2[row] = 2.f * (pD[0][tid] + pD[1][tid]);
    rowB[row]  = pQ[2][tid] + pQ[3][tid];
    rowE2[row] = 2.f * (pD[2][tid] + pD[3][tid]);
  }
}

// ---------------- K2: fused msg+upd, double-buffered async staging ---------
// 2 i-rows/block (R10 winner), 1024 blocks. Per tile: prefetch t+1 to regs,
// j-loop(t), dots+write(t+1), ONE barrier. 8 barriers/block vs R10's 24.
__global__ __launch_bounds__(256) void k_msgdb(
    const float* __restrict__ h, const float* __restrict__ u,
    const float* __restrict__ s, const float* __restrict__ adj,
    const float* __restrict__ rowA, const float* __restrict__ rowB,
    const float* __restrict__ rowD2, const float* __restrict__ rowE2,
    const float* __restrict__ wtilv, const float* __restrict__ g,
    const float* __restrict__ be, const float* __restrict__ wut,
    const float* __restrict__ bu, const float* __restrict__ gu,
    const float* __restrict__ beu, float* __restrict__ out) {
  const int blk = blockIdx.x;            // 1024 = b*128 + ip
  const int b = blk >> 7, ip = blk & 127;
  const int i0 = 2 * ip, i1 = i0 + 1;
  const int tid = threadIdx.x, lane = tid & 63, wv = tid >> 6;
  const int bNN = b * NN;

  __shared__ __align__(16) float st_[2][32 * 132];  // 33.8 KB double buffer
  __shared__ __align__(16) float upair_[2 * DD];    // u~ rows; later comb
  __shared__ __align__(16) float hrow_[2 * DD];
  __shared__ float2 pak0[2][32], pak1[2][32];       // {aJ, rs} per buffer
  __shared__ float pm[2][2], pq[2][2];

  // prologue
  {
    const int ii = tid >> 7, e = tid & 127;
    upair_[ii * DD + e] = u[(size_t)(bNN + i0 + ii) * DD + e];
    hrow_[ii * DD + e]  = h[(size_t)(bNN + i0 + ii) * DD + e];
  }
  const float2 wt2 = *(const float2*)(wtilv + 2 * lane);
  const float2 g2  = *(const float2*)(g + 2 * lane);
  const float2 be2 = *(const float2*)(be + 2 * lane);
  const float C = wave_reduce_add(fmaf(wt2.x, wt2.x, wt2.y * wt2.y));
  const float A0 = rowA[bNN + i0], A1 = rowA[bNN + i1];
  const float D20 = rowD2[bNN + i0], D21 = rowD2[bNN + i1];
  __syncthreads();
  const float2 uu0 = *(const float2*)(&upair_[2 * lane]);
  const float2 uu1 = *(const float2*)(&upair_[DD + 2 * lane]);

  const int j8 = tid >> 3, seg = tid & 7, k0 = seg * 16;
  const float* srcbase = s + (size_t)(bNN + j8) * DD + k0;
  float4 ra, rb, rc, rd;

// stage tile T's fragment (in regs) -> dots vs upair_ -> LDS buf + pak
#define DOTS_WRITE(BUF, T) do {                                               \
    float d0 = 0.f, d1 = 0.f;                                                 \
    const float4 ua0 = *(const float4*)(&upair_[k0]);                         \
    const float4 ua1 = *(const float4*)(&upair_[k0 + 4]);                     \
    const float4 ua2 = *(const float4*)(&upair_[k0 + 8]);                     \
    const float4 ua3 = *(const float4*)(&upair_[k0 + 12]);                    \
    const float4 ub0 = *(const float4*)(&upair_[DD + k0]);                    \
    const float4 ub1 = *(const float4*)(&upair_[DD + k0 + 4]);                \
    const float4 ub2 = *(const float4*)(&upair_[DD + k0 + 8]);                \
    const float4 ub3 = *(const float4*)(&upair_[DD + k0 + 12]);               \
    d0 = fmaf(ra.x, ua0.x, d0); d0 = fmaf(ra.y, ua0.y, d0);                   \
    d0 = fmaf(ra.z, ua0.z, d0); d0 = fmaf(ra.w, ua0.w, d0);                   \
    d0 = fmaf(rb.x, ua1.x, d0); d0 = fmaf(rb.y, ua1.y, d0);                   \
    d0 = fmaf(rb.z, ua1.z, d0); d0 = fmaf(rb.w, ua1.w, d0);                   \
    d0 = fmaf(rc.x, ua2.x, d0); d0 = fmaf(rc.y, ua2.y, d0);                   \
    d0 = fmaf(rc.z, ua2.z, d0); d0 = fmaf(rc.w, ua2.w, d0);                   \
    d0 = fmaf(rd.x, ua3.x, d0); d0 = fmaf(rd.y, ua3.y, d0);                   \
    d0 = fmaf(rd.z, ua3.z, d0); d0 = fmaf(rd.w, ua3.w, d0);                   \
    d1 = fmaf(ra.x, ub0.x, d1); d1 = fmaf(ra.y, ub0.y, d1);                   \
    d1 = fmaf(ra.z, ub0.z, d1); d1 = fmaf(ra.w, ub0.w, d1);                   \
    d1 = fmaf(rb.x, ub1.x, d1); d1 = fmaf(rb.y, ub1.y, d1);                   \
    d1 = fmaf(rb.z, ub1.z, d1); d1 = fmaf(rb.w, ub1.w, d1);                   \
    d1 = fmaf(rc.x, ub2.x, d1); d1 = fmaf(rc.y, ub2.y, d1);                   \
    d1 = fmaf(rc.z, ub2.z, d1); d1 = fmaf(rc.w, ub2.w, d1);                   \
    d1 = fmaf(rd.x, ub3.x, d1); d1 = fmaf(rd.y, ub3.y, d1);                   \
    d1 = fmaf(rd.z, ub3.z, d1); d1 = fmaf(rd.w, ub3.w, d1);                   \
    float* dst = &st_[BUF][j8 * 132 + k0];                                    \
    *(float4*)(dst)      = ra; *(float4*)(dst + 4)  = rb;                     \
    *(float4*)(dst + 8)  = rc; *(float4*)(dst + 12) = rd;                     \
    d0 += __shfl_xor(d0, 1, 64); d1 += __shfl_xor(d1, 1, 64);                 \
    d0 += __shfl_xor(d0, 2, 64); d1 += __shfl_xor(d1, 2, 64);                 \
    d0 += __shfl_xor(d0, 4, 64); d1 += __shfl_xor(d1, 4, 64);                 \
    if (seg == 0) {                                                           \
      const int jg = (T) * 32 + j8;                                           \
      const float Bj = rowB[bNN + jg], E2j = rowE2[bNN + jg];                 \
      const float a0 = adj[(size_t)(bNN + i0) * NN + jg];                     \
      const float a1 = adj[(size_t)(bNN + i1) * NN + jg];                     \
      const float q0 = fmaf(a0, fmaf(a0, C, D20 + E2j), A0 + Bj + 2.f * d0);  \
      const float q1 = fmaf(a1, fmaf(a1, C, D21 + E2j), A1 + Bj + 2.f * d1);  \
      pak0[BUF][j8] = make_float2(a0,                                         \
          __builtin_amdgcn_rsqf(fmaf(q0, 1.f / DD, EPSV)));                   \
      pak1[BUF][j8] = make_float2(a1,                                         \
          __builtin_amdgcn_rsqf(fmaf(q1, 1.f / DD, EPSV)));                   \
    }                                                                         \
  } while (0)

  // stage tile 0
  {
    const float* p = srcbase;
    ra = *(const float4*)(p);     rb = *(const float4*)(p + 4);
    rc = *(const float4*)(p + 8); rd = *(const float4*)(p + 12);
  }
  DOTS_WRITE(0, 0);
  __syncthreads();

  float accA0 = 0.f, accA1 = 0.f, accB0 = 0.f, accB1 = 0.f;
  int cur = 0;

  for (int t = 0; t < 8; ++t) {
    if (t < 7) {                         // issue next tile's loads early
      const float* p = srcbase + (size_t)(t + 1) * 32 * DD;
      ra = *(const float4*)(p);     rb = *(const float4*)(p + 4);
      rc = *(const float4*)(p + 8); rd = *(const float4*)(p + 12);
    }
    // j-loop on tile t from buffer cur
    {
      const float* stc = st_[cur];
      const float2* p0 = pak0[cur];
      const float2* p1 = pak1[cur];
      const int t0 = t * 32;
      for (int jj = wv; jj < 32; jj += 4) {
        const int jg = t0 + jj;
        const float2 ss = *(const float2*)(&stc[jj * 132 + 2 * lane]);
        const float sx0 = uu0.x + ss.x, sx1 = uu0.y + ss.y;
        const float tx0 = uu1.x + ss.x, tx1 = uu1.y + ss.y;
        if (jg != i0) {                  // wave-uniform
          const float2 p = p0[jj];
          const float x0 = fmaf(p.x, wt2.x, sx0);
          const float x1 = fmaf(p.x, wt2.y, sx1);
          const float y0 = fmaf(x0 * p.y, g2.x, be2.x);
          const float y1 = fmaf(x1 * p.y, g2.y, be2.y);
          accA0 = fmaf(y0, __builtin_amdgcn_rcpf(1.f + __expf(-y0)), accA0);
          accA1 = fmaf(y1, __builtin_amdgcn_rcpf(1.f + __expf(-y1)), accA1);
        }
        if (jg != i1) {
          const float2 p = p1[jj];
          const float x0 = fmaf(p.x, wt2.x, tx0);
          const float x1 = fmaf(p.x, wt2.y, tx1);
          const float y0 = fmaf(x0 * p.y, g2.x, be2.x);
          const float y1 = fmaf(x1 * p.y, g2.y, be2.y);
          accB0 = fmaf(y0, __builtin_amdgcn_rcpf(1.f + __expf(-y0)), accB0);
          accB1 = fmaf(y1, __builtin_amdgcn_rcpf(1.f + __expf(-y1)), accB1);
        }
      }
    }
    if (t < 7) {
      DOTS_WRITE(cur ^ 1, t + 1);
      __syncthreads();                   // one barrier per tile
      cur ^= 1;
    }
  }

  // reduce 4 waves -> agg rows (overlay in st_[0])
  __syncthreads();                       // all j-loops done reading st_
  *(float2*)(&st_[0][(wv * 2 + 0) * DD + 2 * lane]) = make_float2(accA0, accA1);
  *(float2*)(&st_[0][(wv * 2 + 1) * DD + 2 * lane]) = make_float2(accB0, accB1);
  __syncthreads();
  {
    const int ii = tid >> 7, e = tid & 127;
    st_[0][(8 + ii) * DD + e] = st_[0][(0 + ii) * DD + e] +
                                st_[0][(2 + ii) * DD + e] +
                                st_[0][(4 + ii) * DD + e] +
                                st_[0][(6 + ii) * DD + e];
  }
  __syncthreads();

  // upd tail: v[e] = bu[e] + h.Wu1 + agg.Wu2 (split halves), W streamed once
  const int half = tid >> 7, e = tid & 127;
  float v0 = (half == 0) ? bu[e] : 0.f;
  float v1 = v0;
  {
    const float* xin = (half == 0) ? hrow_ : &st_[0][8 * DD];
    const float* wcol = wut + (size_t)half * DD * DD + e;
#pragma unroll 8
    for (int k = 0; k < DD; ++k) {
      const float w = wcol[(size_t)k * DD];
      v0 = fmaf(xin[k], w, v0);
      v1 = fmaf(xin[DD + k], w, v1);
    }
  }
  if (half == 1) { upair_[e] = v0; upair_[DD + e] = v1; }  // comb
  __syncthreads();
  if (half == 0) {
    v0 += upair_[e];
    v1 += upair_[DD + e];
    const float sm0 = wave_reduce_add(v0), sq0 = wave_reduce_add(v0 * v0);
    const float sm1 = wave_reduce_add(v1), sq1 = wave_reduce_add(v1 * v1);
    if (lane == 0) {
      pm[wv][0] = sm0; pq[wv][0] = sq0;
      pm[wv][1] = sm1; pq[wv][1] = sq1;
    }
  }
  __syncthreads();
  if (half == 0) {
    const float ge = gu[e], bee = beu[e];
    {
      const float mean = (pm[0][0] + pm[1][0]) * (1.f / DD);
      const float var = (pq[0][0] + pq[1][0]) * (1.f / DD) - mean * mean;
      const float rs = __builtin_amdgcn_rsqf(var + EPSV);
      const float y = fmaf((v0 - mean) * rs, ge, bee);
      const float sg = __builtin_amdgcn_rcpf(1.f + __expf(-y));
      out[(size_t)(bNN + i0) * DD + e] = hrow_[e] + y * sg;
    }
    {
      const float mean = (pm[0][1] + pm[1][1]) * (1.f / DD);
      const float var = (pq[0][1] + pq[1][1]) * (1.f / DD) - mean * mean;
      const float rs = __builtin_amdgcn_rsqf(var + EPSV);
      const float y = fmaf((v1 - mean) * rs, ge, bee);
      const float sg = __builtin_amdgcn_rcpf(1.f + __expf(-y));
      out[(size_t)(bNN + i1) * DD + e] = hrow_[DD + e] + y * sg;
    }
  }
}

extern "C" void kernel_launch(void* const* d_in, const int* in_sizes, int n_in,
                              void* d_out, int out_size, void* d_ws, size_t ws_size,
                              hipStream_t stream) {
  const float* h    = (const float*)d_in[0];
  const float* adj  = (const float*)d_in[1];
  const float* Wm   = (const float*)d_in[2];
  const float* bmsg = (const float*)d_in[3];
  const float* gmsg = (const float*)d_in[4];
  const float* bemsg= (const float*)d_in[5];
  const float* Wu   = (const float*)d_in[6];
  const float* bupd = (const float*)d_in[7];
  const float* gupd = (const float*)d_in[8];
  const float* beupd= (const float*)d_in[9];
  float* out = (float*)d_out;

  float* ws    = (float*)d_ws;
  float* u     = ws;                        // 262144
  float* s     = u + BB * NN * DD;          // 262144
  float* rowA  = s + BB * NN * DD;          // 2048
  float* rowB  = rowA + BB * NN;            // 2048
  float* rowD2 = rowB + BB * NN;            // 2048
  float* rowE2 = rowD2 + BB * NN;           // 2048
  float* wtilv = rowE2 + BB * NN;           // 128
  float* wut   = wtilv + DD;                // 32768

  k_proj<<<512, 256, 0, stream>>>(h, Wm, bmsg, Wu, u, s, rowA, rowB, rowD2,
                                  rowE2, wtilv, wut);
  k_msgdb<<<1024, 256, 0, stream>>>(h, u, s, adj, rowA, rowB, rowD2, rowE2,
                                    wtilv, gmsg, bemsg, wut, bupd, gupd,
                                    beupd, out);
}